// Round 6
// baseline (239.342 us; speedup 1.0000x reference)
//
#include <hip/hip_runtime.h>
#include <hip/hip_bf16.h>

#define GAT_ALPHA 0.2f
#define LOG2E 1.4426950408889634f

typedef float f32x4 __attribute__((ext_vector_type(4)));
typedef int   i32x4 __attribute__((ext_vector_type(4)));
typedef short bf16x8 __attribute__((ext_vector_type(8)));

static constexpr int Nn  = 2048;
static constexpr int FIN = 256;
static constexpr int FO  = 128;

static __device__ __forceinline__ unsigned short f2bf(float x) {
    __hip_bfloat16 h = __float2bfloat16(x);
    return __builtin_bit_cast(unsigned short, h);
}
static __device__ __forceinline__ float bf2f(unsigned short u) {
    unsigned int v = ((unsigned int)u) << 16;
    return __builtin_bit_cast(float, v);
}

// ---------------------------------------------------------------------------
// Kernel 0 (prep): wa = W@a (both halves). Inits md_key[8] = 0 (key of -inf).
// ---------------------------------------------------------------------------
__global__ __launch_bounds__(256) void gat_prep(
        const float* __restrict__ W, const float* __restrict__ a,
        float* __restrict__ wa, unsigned int* __restrict__ md_key)
{
    __shared__ float pr[32][8];
    __shared__ float pd[32][8];
    const int t = threadIdx.x;
    const int kl = t >> 3, seg = t & 7;
    const int k = blockIdx.x * 32 + kl;
    float ps = 0.f, pv = 0.f;
    const float* wr = W + (size_t)k * FO + seg * 16;
    #pragma unroll
    for (int f = 0; f < 16; f += 4) {
        f32x4 wv = *(const f32x4*)(wr + f);
        f32x4 as = *(const f32x4*)(a + seg * 16 + f);
        f32x4 ad = *(const f32x4*)(a + FO + seg * 16 + f);
        ps += wv[0]*as[0] + wv[1]*as[1] + wv[2]*as[2] + wv[3]*as[3];
        pv += wv[0]*ad[0] + wv[1]*ad[1] + wv[2]*ad[2] + wv[3]*ad[3];
    }
    pr[kl][seg] = ps; pd[kl][seg] = pv;
    __syncthreads();
    if (t < 32) {
        float s = 0.f, d = 0.f;
        #pragma unroll
        for (int j = 0; j < 8; ++j) { s += pr[t][j]; d += pd[t][j]; }
        wa[blockIdx.x * 32 + t]       = s;
        wa[256 + blockIdx.x * 32 + t] = d;
    }
    if (blockIdx.x == 0 && t < 8) md_key[t] = 0u;   // key(-inf)
}

// ---------------------------------------------------------------------------
// Kernel 1: Wp = bf16(h@W) in PACKED MFMA-B-fragment layout:
//   elem index ((b*64 + v)*8 + nt)*512 + lane*8 + e, where for feature f and
//   node n: v=n>>5, nt=f>>4, lane=((n>>3)&3)*16 + (f&15), e=n&7.
// s_src/s_dst fp32-exact via wa; per-batch max(s_dst) via uint atomicMax.
// ---------------------------------------------------------------------------
__global__ __launch_bounds__(256) void gat_wh(
        const float* __restrict__ h, const float* __restrict__ W,
        const float* __restrict__ wa, unsigned short* __restrict__ Wp,
        float* __restrict__ s_src, float* __restrict__ s_dst,
        unsigned int* __restrict__ md_key)
{
    __shared__ unsigned short WT[FO][264];  // [f][k] bf16, padded
    __shared__ float wal[512];
    __shared__ float sred[64][4][2];
    __shared__ float red64[64];
    const int t  = threadIdx.x;
    const int b  = blockIdx.x & 7;
    const int n0 = (blockIdx.x >> 3) << 6;

    if (t < 128) *(f32x4*)&wal[t * 4] = *(const f32x4*)&wa[t * 4];
    #pragma unroll
    for (int c = 0; c < 32; ++c) {
        int flat = c * 1024 + t * 4;
        int k = flat >> 7, f = flat & 127;
        f32x4 wv = *(const f32x4*)&W[flat];
        WT[f + 0][k] = f2bf(wv[0]);
        WT[f + 1][k] = f2bf(wv[1]);
        WT[f + 2][k] = f2bf(wv[2]);
        WT[f + 3][k] = f2bf(wv[3]);
    }
    __syncthreads();

    {
        const int row = t >> 2, seg = t & 3;
        const float* hp  = h + ((size_t)(b * Nn + n0 + row)) * FIN + seg * 64;
        const float* was = &wal[seg * 64];
        const float* wad = &wal[256 + seg * 64];
        float ps = 0.f, pv = 0.f;
        #pragma unroll
        for (int j = 0; j < 64; j += 4) {
            f32x4 hv = *(const f32x4*)(hp + j);
            f32x4 sv = *(const f32x4*)(was + j);
            f32x4 dv = *(const f32x4*)(wad + j);
            ps += hv[0]*sv[0] + hv[1]*sv[1] + hv[2]*sv[2] + hv[3]*sv[3];
            pv += hv[0]*dv[0] + hv[1]*dv[1] + hv[2]*dv[2] + hv[3]*dv[3];
        }
        sred[row][seg][0] = ps;
        sred[row][seg][1] = pv;
    }
    __syncthreads();
    if (t < 64) {
        float s = sred[t][0][0] + sred[t][1][0] + sred[t][2][0] + sred[t][3][0];
        float d = sred[t][0][1] + sred[t][1][1] + sred[t][2][1] + sred[t][3][1];
        s_src[b * Nn + n0 + t] = s;
        s_dst[b * Nn + n0 + t] = d;
        red64[t] = d;
    }
    __syncthreads();
    if (t < 16) red64[t] = fmaxf(fmaxf(red64[t], red64[t + 16]),
                                 fmaxf(red64[t + 32], red64[t + 48]));
    __syncthreads();
    if (t == 0) {
        float m = red64[0];
        #pragma unroll
        for (int j = 1; j < 16; ++j) m = fmaxf(m, red64[j]);
        unsigned int bits = __builtin_bit_cast(unsigned int, m);
        unsigned int key  = (bits & 0x80000000u) ? ~bits : (bits | 0x80000000u);
        atomicMax(md_key + b, key);
    }

    const int w = t >> 6, lane = t & 63, n16 = lane & 15, quad = lane >> 4;
    const float* ha = h + ((size_t)(b * Nn + n0 + w * 16 + n16)) * FIN + quad * 8;
    f32x4 acc[8] = {};
    #pragma unroll
    for (int ks = 0; ks < 8; ++ks) {
        f32x4 h0 = *(const f32x4*)(ha + ks * 32);
        f32x4 h1 = *(const f32x4*)(ha + ks * 32 + 4);
        bf16x8 af;
        af[0] = (short)f2bf(h0[0]); af[1] = (short)f2bf(h0[1]);
        af[2] = (short)f2bf(h0[2]); af[3] = (short)f2bf(h0[3]);
        af[4] = (short)f2bf(h1[0]); af[5] = (short)f2bf(h1[1]);
        af[6] = (short)f2bf(h1[2]); af[7] = (short)f2bf(h1[3]);
        #pragma unroll
        for (int nt = 0; nt < 8; ++nt) {
            bf16x8 bfr = *(const bf16x8*)&WT[nt * 16 + n16][ks * 32 + quad * 8];
            acc[nt] = __builtin_amdgcn_mfma_f32_16x16x32_bf16(af, bfr, acc[nt], 0, 0, 0);
        }
    }
    // packed write: element (f = nt*16+n16, n = n0 + w*16 + quad*4 + rr)
    {
        const int v      = (n0 >> 5) + (w >> 1);
        const int quad_p = ((w & 1) << 1) + (quad >> 1);
        const int eoff   = (quad & 1) << 2;
        #pragma unroll
        for (int nt = 0; nt < 8; ++nt) {
            ushort4 pk;
            pk.x = f2bf(acc[nt][0]); pk.y = f2bf(acc[nt][1]);
            pk.z = f2bf(acc[nt][2]); pk.w = f2bf(acc[nt][3]);
            size_t idx = ((((size_t)(b << 6) + v) * 8 + nt) * 64 + quad_p * 16 + n16) * 8 + eoff;
            *(ushort4*)&Wp[idx] = pk;
        }
    }
}

// ---------------------------------------------------------------------------
// Kernel 2 (v9): same fused-ballot pipelined structure as v8, but
// re-partitioned into TWO independent barrier domains per CU:
// 32-row i-tiles x 256 threads (4 waves = 2 row-groups x 2 j-windows),
// grid 512 = 64 i-tiles x 8 batches -> 2 blocks/CU (~50 KB LDS each).
// While one block drains its barrier/vmcnt, the other issues VMEM+MFMA.
// Wave w ballot-packs local adj rows [w*8, w*8+8) pipelined 3 deep;
// Wp staged via conflict-free linear ds_writes (4 x 16 B/thread).
// ---------------------------------------------------------------------------
__global__ __launch_bounds__(256, 2) void gat_attn(
        const int* __restrict__ adj, const unsigned short* __restrict__ Wp,
        const float* __restrict__ s_src, const float* __restrict__ s_dst,
        const unsigned int* __restrict__ md_key, float* __restrict__ out)
{
    constexpr int AS = 132;                      // accbuf row stride (f32)
    constexpr int MS = 68;                       // mask row stride (words)
    __shared__ __align__(16) float smem_f[8192];           // 32768 B: stage bufs / accbuf
    __shared__ __align__(16) unsigned int mlds[32 * MS];   // 8704 B
    __shared__ __align__(16) float dlds[Nn];               // 8192 B
    __shared__ float l_red[32];
    unsigned short* ldsw = (unsigned short*)smem_f;        // 2 x 8192 shorts

    const int t = threadIdx.x, w = t >> 6, lane = t & 63;
    const int n16 = lane & 15, quad = lane >> 4;
    const int rg = w & 1, jwin = w >> 1;
    const int b  = blockIdx.x & 7;
    const int i0 = (blockIdx.x >> 3) << 5;

    if (t < 32) l_red[t] = 0.f;

    // per-wave adj base: wave w owns local rows [w*8, w*8+8)
    const int* abase = adj + ((size_t)(b * Nn + i0 + w * 8)) * Nn + lane;
    // packed Wp batch base
    const unsigned short* wsrc = Wp + ((size_t)b << 18);

    // ---- prologue ----
    // Wp tile-0 stage loads first (oldest vmcnt -> earliest ds_write)
    f32x4 pg[4];
    #pragma unroll
    for (int p = 0; p < 4; ++p) pg[p] = *(const f32x4*)(wsrc + p * 2048 + t * 8);
    // pack chunks 0,1 for this wave's 8 rows
    int pv[16];
    #pragma unroll
    for (int k = 0; k < 16; ++k) {
        const int rr = k & 7, c = k >> 3;
        pv[k] = abase[(size_t)rr * Nn + (c << 6)];
    }
    // chunk-2 loads (consumed by ballot at iter 0)
    int avQ[8], avP[8];
    #pragma unroll
    for (int rr = 0; rr < 8; ++rr) avQ[rr] = abase[(size_t)rr * Nn + 128];
    // s_dst stage (256 thr x 8 floats)
    *(f32x4*)&dlds[t * 8]     = *(const f32x4*)(s_dst + b * Nn + t * 8);
    *(f32x4*)&dlds[t * 8 + 4] = *(const f32x4*)(s_dst + b * Nn + t * 8 + 4);

    const unsigned int key = md_key[b];
    const unsigned int mb  = (key & 0x80000000u) ? (key ^ 0x80000000u) : ~key;
    const float mdb = __builtin_bit_cast(float, mb);
    const int row = i0 + rg * 16 + n16;          // this lane's i-row
    const float ssr = s_src[b * Nn + row];
    const float tm  = ssr + mdb;
    const float mi  = fmaxf(tm, GAT_ALPHA * tm) * LOG2E;   // row upper bound
    const float sL  = ssr * LOG2E;
    const int jw   = (jwin << 5) + (quad << 3);  // lane's j offset within tile
    const int mrow = (rg * 16 + n16) * MS;

    // ballot+write chunks 0,1
    #pragma unroll
    for (int k = 0; k < 16; ++k) {
        const int rr = k & 7, c = k >> 3;
        unsigned long long m = __ballot(pv[k] > 0);
        if (lane == 0) mlds[(w * 8 + rr) * MS + (c << 1)]     = (unsigned int)m;
        if (lane == 1) mlds[(w * 8 + rr) * MS + (c << 1) + 1] = (unsigned int)(m >> 32);
    }
    // Wp tile-0 ds_write (conflict-free: 16 B linear per thread, four passes)
    #pragma unroll
    for (int p = 0; p < 4; ++p)
        *(f32x4*)&ldsw[p * 2048 + t * 8] = pg[p];

    f32x4 acc[8] = {};
    float ls = 0.f;
    __syncthreads();

    // ---- main loop: 2 tiles per iteration (static av double-buffer) ----
#define GAT_TILE(S, CUR, AV_ISSUE, AV_BALLOT)                                   \
    {                                                                           \
        const int s_ = (S);                                                     \
        const int j0_ = s_ << 6;                                                \
        const unsigned int mword = mlds[mrow + (s_ << 1) + jwin];               \
        const unsigned int mbyte = (mword >> (quad * 8)) & 0xffu;               \
        f32x4 d0 = *(const f32x4*)&dlds[j0_ + jw];                              \
        f32x4 d1 = *(const f32x4*)&dlds[j0_ + jw + 4];                          \
        /* adj loads for chunk s+3 (oldest VMEM this iter) */                   \
        if (s_ < 29) {                                                          \
            const int off_ = (s_ + 3) << 6;                                     \
            _Pragma("unroll")                                                   \
            for (int rr = 0; rr < 8; ++rr)                                      \
                AV_ISSUE[rr] = abase[(size_t)rr * Nn + off_];                   \
        }                                                                       \
        /* Wp stage loads for tile s+1 */                                       \
        f32x4 g[4];                                                             \
        if (s_ < 31) {                                                          \
            const unsigned short* src_ = wsrc + (size_t)(s_ + 1) * 8192;        \
            _Pragma("unroll")                                                   \
            for (int p = 0; p < 4; ++p)                                         \
                g[p] = *(const f32x4*)(src_ + p * 2048 + t * 8);                \
        }                                                                       \
        /* exp -> A fragment */                                                 \
        bf16x8 af;                                                              \
        _Pragma("unroll")                                                       \
        for (int j = 0; j < 4; ++j) {                                           \
            float u  = __builtin_fmaf(d0[j], LOG2E, sL);                        \
            float lr = fmaxf(u, GAT_ALPHA * u);                                 \
            float e  = __builtin_amdgcn_exp2f(lr - mi);                         \
            e = ((mbyte >> j) & 1u) ? e : 0.f;                                  \
            unsigned short us = f2bf(e);                                        \
            ls += bf2f(us); af[j] = (short)us;                                  \
        }                                                                       \
        _Pragma("unroll")                                                       \
        for (int j = 0; j < 4; ++j) {                                           \
            float u  = __builtin_fmaf(d1[j], LOG2E, sL);                        \
            float lr = fmaxf(u, GAT_ALPHA * u);                                 \
            float e  = __builtin_amdgcn_exp2f(lr - mi);                         \
            e = ((mbyte >> (4 + j)) & 1u) ? e : 0.f;                            \
            unsigned short us = f2bf(e);                                        \
            ls += bf2f(us); af[4 + j] = (short)us;                              \
        }                                                                       \
        /* B fragments from LDS + MFMA */                                       \
        const unsigned short* bbase = &ldsw[(CUR) * 8192 + (jwin << 12) + (lane << 3)]; \
        _Pragma("unroll")                                                       \
        for (int nt = 0; nt < 8; ++nt) {                                        \
            bf16x8 bfr = *(const bf16x8*)(bbase + (nt << 9));                   \
            acc[nt] = __builtin_amdgcn_mfma_f32_16x16x32_bf16(af, bfr, acc[nt], 0, 0, 0); \
        }                                                                       \
        /* ballot chunk s+2 (loads issued last iter) + mask write */            \
        if (s_ < 30) {                                                          \
            const int cw_ = (s_ + 2) << 1;                                      \
            _Pragma("unroll")                                                   \
            for (int rr = 0; rr < 8; ++rr) {                                    \
                unsigned long long m = __ballot(AV_BALLOT[rr] > 0);             \
                if (lane == 0) mlds[(w * 8 + rr) * MS + cw_]     = (unsigned int)m; \
                if (lane == 1) mlds[(w * 8 + rr) * MS + cw_ + 1] = (unsigned int)(m >> 32); \
            }                                                                   \
        }                                                                       \
        /* late Wp stage write into other buffer (conflict-free) */             \
        if (s_ < 31) {                                                          \
            _Pragma("unroll")                                                   \
            for (int p = 0; p < 4; ++p)                                         \
                *(f32x4*)&ldsw[((CUR) ^ 1) * 8192 + p * 2048 + t * 8] = g[p];   \
        }                                                                       \
        __syncthreads();                                                        \
    }

    for (int s = 0; s < 32; s += 2) {
        GAT_TILE(s,     0, avP, avQ)
        GAT_TILE(s + 1, 1, avQ, avP)
    }
#undef GAT_TILE

    // denominator: reduce per-lane partials across quads; 2 waves per row-group
    ls += __shfl_xor(ls, 16); ls += __shfl_xor(ls, 32);
    if (quad == 0) atomicAdd(&l_red[rg * 16 + n16], ls);

    // cross-wave acc reduction: jwin 0 writes, jwin 1 adds (accbuf aliases stage)
    float* slotp = smem_f + (size_t)(rg * 16) * AS;
    if (jwin == 0) {
        #pragma unroll
        for (int nt = 0; nt < 8; ++nt)
            #pragma unroll
            for (int rr = 0; rr < 4; ++rr)
                slotp[(quad * 4 + rr) * AS + nt * 16 + n16] = acc[nt][rr];
    }
    __syncthreads();
    if (jwin == 1) {
        #pragma unroll
        for (int nt = 0; nt < 8; ++nt)
            #pragma unroll
            for (int rr = 0; rr < 4; ++rr)
                slotp[(quad * 4 + rr) * AS + nt * 16 + n16] += acc[nt][rr];
    }
    __syncthreads();

    // normalize + ELU + coalesced store (32 rows x 128 f)
    float* ob = out + ((size_t)(b * Nn + i0)) * FO;
    #pragma unroll
    for (int c = 0; c < 4; ++c) {
        int flat = c * 1024 + t * 4;
        int m = flat >> 7, f = flat & 127;
        f32x4 v = *(const f32x4*)&smem_f[(size_t)m * AS + f];
        float l = l_red[m];
        f32x4 o;
        #pragma unroll
        for (int j = 0; j < 4; ++j) {
            float x = v[j] / l;
            o[j] = x > 0.f ? x : expm1f(x);
        }
        *(f32x4*)&ob[(size_t)m * FO + f] = o;
    }
}

extern "C" void kernel_launch(void* const* d_in, const int* in_sizes, int n_in,
                              void* d_out, int out_size, void* d_ws, size_t ws_size,
                              hipStream_t stream)
{
    const float* h   = (const float*)d_in[0];
    const int*   adj = (const int*)d_in[1];
    const float* W   = (const float*)d_in[2];
    const float* a   = (const float*)d_in[3];
    float* out = (float*)d_out;

    char* ws = (char*)d_ws;
    unsigned short* Wp  = (unsigned short*)ws;                    // 4 MiB packed
    float* s_src        = (float*)(ws + 4194304);                 // 8 KiB
    float* s_dst        = (float*)(ws + 4259840);                 // 8 KiB
    float* wa           = (float*)(ws + 4325376);                 // 2 KiB
    unsigned int* md_key= (unsigned int*)(ws + 4327424);          // 32 B

    hipLaunchKernelGGL(gat_prep, dim3(8),   dim3(256), 0, stream, W, a, wa, md_key);
    hipLaunchKernelGGL(gat_wh,   dim3(256), dim3(256), 0, stream, h, W, wa, Wp, s_src, s_dst, md_key);
    hipLaunchKernelGGL(gat_attn, dim3(512), dim3(256), 0, stream, adj, Wp, s_src, s_dst, md_key, out);
}

// Round 7
// 236.165 us; speedup vs baseline: 1.0135x; 1.0135x over previous
//
#include <hip/hip_runtime.h>
#include <hip/hip_bf16.h>

#define GAT_ALPHA 0.2f
#define LOG2E 1.4426950408889634f

typedef float f32x4 __attribute__((ext_vector_type(4)));
typedef int   i32x4 __attribute__((ext_vector_type(4)));
typedef short bf16x8 __attribute__((ext_vector_type(8)));

static constexpr int Nn  = 2048;
static constexpr int FIN = 256;
static constexpr int FO  = 128;

static __device__ __forceinline__ unsigned short f2bf(float x) {
    __hip_bfloat16 h = __float2bfloat16(x);
    return __builtin_bit_cast(unsigned short, h);
}
static __device__ __forceinline__ float bf2f(unsigned short u) {
    unsigned int v = ((unsigned int)u) << 16;
    return __builtin_bit_cast(float, v);
}

// ---------------------------------------------------------------------------
// Kernel 0 (prep): wa = W@a (both halves). Inits md_key[8] = 0 (key of -inf).
// ---------------------------------------------------------------------------
__global__ __launch_bounds__(256) void gat_prep(
        const float* __restrict__ W, const float* __restrict__ a,
        float* __restrict__ wa, unsigned int* __restrict__ md_key)
{
    __shared__ float pr[32][8];
    __shared__ float pd[32][8];
    const int t = threadIdx.x;
    const int kl = t >> 3, seg = t & 7;
    const int k = blockIdx.x * 32 + kl;
    float ps = 0.f, pv = 0.f;
    const float* wr = W + (size_t)k * FO + seg * 16;
    #pragma unroll
    for (int f = 0; f < 16; f += 4) {
        f32x4 wv = *(const f32x4*)(wr + f);
        f32x4 as = *(const f32x4*)(a + seg * 16 + f);
        f32x4 ad = *(const f32x4*)(a + FO + seg * 16 + f);
        ps += wv[0]*as[0] + wv[1]*as[1] + wv[2]*as[2] + wv[3]*as[3];
        pv += wv[0]*ad[0] + wv[1]*ad[1] + wv[2]*ad[2] + wv[3]*ad[3];
    }
    pr[kl][seg] = ps; pd[kl][seg] = pv;
    __syncthreads();
    if (t < 32) {
        float s = 0.f, d = 0.f;
        #pragma unroll
        for (int j = 0; j < 8; ++j) { s += pr[t][j]; d += pd[t][j]; }
        wa[blockIdx.x * 32 + t]       = s;
        wa[256 + blockIdx.x * 32 + t] = d;
    }
    if (blockIdx.x == 0 && t < 8) md_key[t] = 0u;   // key(-inf)
}

// ---------------------------------------------------------------------------
// Kernel 1: Wp = bf16(h@W) in PACKED MFMA-B-fragment layout:
//   elem index ((b*64 + v)*8 + nt)*512 + lane*8 + e, where for feature f and
//   node n: v=n>>5, nt=f>>4, lane=((n>>3)&3)*16 + (f&15), e=n&7.
// s_src/s_dst fp32-exact via wa; per-batch max(s_dst) via uint atomicMax.
// ---------------------------------------------------------------------------
__global__ __launch_bounds__(256) void gat_wh(
        const float* __restrict__ h, const float* __restrict__ W,
        const float* __restrict__ wa, unsigned short* __restrict__ Wp,
        float* __restrict__ s_src, float* __restrict__ s_dst,
        unsigned int* __restrict__ md_key)
{
    __shared__ unsigned short WT[FO][264];  // [f][k] bf16, padded
    __shared__ float wal[512];
    __shared__ float sred[64][4][2];
    __shared__ float red64[64];
    const int t  = threadIdx.x;
    const int b  = blockIdx.x & 7;
    const int n0 = (blockIdx.x >> 3) << 6;

    if (t < 128) *(f32x4*)&wal[t * 4] = *(const f32x4*)&wa[t * 4];
    #pragma unroll
    for (int c = 0; c < 32; ++c) {
        int flat = c * 1024 + t * 4;
        int k = flat >> 7, f = flat & 127;
        f32x4 wv = *(const f32x4*)&W[flat];
        WT[f + 0][k] = f2bf(wv[0]);
        WT[f + 1][k] = f2bf(wv[1]);
        WT[f + 2][k] = f2bf(wv[2]);
        WT[f + 3][k] = f2bf(wv[3]);
    }
    __syncthreads();

    {
        const int row = t >> 2, seg = t & 3;
        const float* hp  = h + ((size_t)(b * Nn + n0 + row)) * FIN + seg * 64;
        const float* was = &wal[seg * 64];
        const float* wad = &wal[256 + seg * 64];
        float ps = 0.f, pv = 0.f;
        #pragma unroll
        for (int j = 0; j < 64; j += 4) {
            f32x4 hv = *(const f32x4*)(hp + j);
            f32x4 sv = *(const f32x4*)(was + j);
            f32x4 dv = *(const f32x4*)(wad + j);
            ps += hv[0]*sv[0] + hv[1]*sv[1] + hv[2]*sv[2] + hv[3]*sv[3];
            pv += hv[0]*dv[0] + hv[1]*dv[1] + hv[2]*dv[2] + hv[3]*dv[3];
        }
        sred[row][seg][0] = ps;
        sred[row][seg][1] = pv;
    }
    __syncthreads();
    if (t < 64) {
        float s = sred[t][0][0] + sred[t][1][0] + sred[t][2][0] + sred[t][3][0];
        float d = sred[t][0][1] + sred[t][1][1] + sred[t][2][1] + sred[t][3][1];
        s_src[b * Nn + n0 + t] = s;
        s_dst[b * Nn + n0 + t] = d;
        red64[t] = d;
    }
    __syncthreads();
    if (t < 16) red64[t] = fmaxf(fmaxf(red64[t], red64[t + 16]),
                                 fmaxf(red64[t + 32], red64[t + 48]));
    __syncthreads();
    if (t == 0) {
        float m = red64[0];
        #pragma unroll
        for (int j = 1; j < 16; ++j) m = fmaxf(m, red64[j]);
        unsigned int bits = __builtin_bit_cast(unsigned int, m);
        unsigned int key  = (bits & 0x80000000u) ? ~bits : (bits | 0x80000000u);
        atomicMax(md_key + b, key);
    }

    const int w = t >> 6, lane = t & 63, n16 = lane & 15, quad = lane >> 4;
    const float* ha = h + ((size_t)(b * Nn + n0 + w * 16 + n16)) * FIN + quad * 8;
    f32x4 acc[8] = {};
    #pragma unroll
    for (int ks = 0; ks < 8; ++ks) {
        f32x4 h0 = *(const f32x4*)(ha + ks * 32);
        f32x4 h1 = *(const f32x4*)(ha + ks * 32 + 4);
        bf16x8 af;
        af[0] = (short)f2bf(h0[0]); af[1] = (short)f2bf(h0[1]);
        af[2] = (short)f2bf(h0[2]); af[3] = (short)f2bf(h0[3]);
        af[4] = (short)f2bf(h1[0]); af[5] = (short)f2bf(h1[1]);
        af[6] = (short)f2bf(h1[2]); af[7] = (short)f2bf(h1[3]);
        #pragma unroll
        for (int nt = 0; nt < 8; ++nt) {
            bf16x8 bfr = *(const bf16x8*)&WT[nt * 16 + n16][ks * 32 + quad * 8];
            acc[nt] = __builtin_amdgcn_mfma_f32_16x16x32_bf16(af, bfr, acc[nt], 0, 0, 0);
        }
    }
    // packed write: element (f = nt*16+n16, n = n0 + w*16 + quad*4 + rr)
    {
        const int v      = (n0 >> 5) + (w >> 1);
        const int quad_p = ((w & 1) << 1) + (quad >> 1);
        const int eoff   = (quad & 1) << 2;
        #pragma unroll
        for (int nt = 0; nt < 8; ++nt) {
            ushort4 pk;
            pk.x = f2bf(acc[nt][0]); pk.y = f2bf(acc[nt][1]);
            pk.z = f2bf(acc[nt][2]); pk.w = f2bf(acc[nt][3]);
            size_t idx = ((((size_t)(b << 6) + v) * 8 + nt) * 64 + quad_p * 16 + n16) * 8 + eoff;
            *(ushort4*)&Wp[idx] = pk;
        }
    }
}

// ---------------------------------------------------------------------------
// Kernel 2 (v10): 128-j tiles (16 iters) x 64-row blocks; 8 waves =
// 2 row-groups(32 rows) x 4 j-windows. Each wave computes TWO A-fragments
// (rows rg*32+n16, +16) per B-fragment read -> B-frag LDS traffic per
// j-column halved; 16 MFMA/wave/tile. adj ballot-pack fused WITHIN each
// tile: loads issued at tile top, balloted at tile bottom -- per-tile
// compute (~1300+ cy) now exceeds HBM latency, so plain __syncthreads'
// vmcnt drain costs ~nothing. Stage dbuf 64 KB, conflict-free linear
// ds_writes. Grid 256 = 32 i-tiles x 8 batches (batch==XCD), 1 block/CU.
// ---------------------------------------------------------------------------
__global__ __launch_bounds__(512, 2) void gat_attn(
        const int* __restrict__ adj, const unsigned short* __restrict__ Wp,
        const float* __restrict__ s_src, const float* __restrict__ s_dst,
        const unsigned int* __restrict__ md_key, float* __restrict__ out)
{
    constexpr int AS = 132;                      // accbuf row stride (f32)
    constexpr int MS = 68;                       // mask row stride (words)
    __shared__ __align__(16) float smem_f[2 * 64 * AS];     // 67584 B: stage bufs / acc slots
    __shared__ __align__(16) unsigned int mlds[64 * MS];    // 17408 B
    __shared__ __align__(16) float dlds[Nn];                // 8192 B
    __shared__ float l_red[64];
    unsigned short* ldsw = (unsigned short*)smem_f;         // 2 x 16384 shorts

    const int t = threadIdx.x, w = t >> 6, lane = t & 63;
    const int n16 = lane & 15, quad = lane >> 4;
    const int rg = w & 1, jwin = w >> 1;         // 2 row-groups x 4 j-windows
    const int b  = blockIdx.x & 7;
    const int i0 = (blockIdx.x >> 3) << 6;

    if (t < 64) l_red[t] = 0.f;

    // per-wave adj base: wave w ballot-packs local rows [w*8, w*8+8)
    const int* abase = adj + ((size_t)(b * Nn + i0 + w * 8)) * Nn + lane;
    const unsigned short* wsrc = Wp + ((size_t)b << 18);

    // ---- prologue ----
    // adj tile-0 loads (issued first: balloted below after other issues)
    int av[16];
    #pragma unroll
    for (int k = 0; k < 16; ++k)
        av[k] = abase[(size_t)(k >> 1) * Nn + ((k & 1) << 6)];
    // Wp tile-0 stage loads (32 KB, 64 B/thread)
    f32x4 pg[4];
    #pragma unroll
    for (int p = 0; p < 4; ++p)
        pg[p] = *(const f32x4*)(wsrc + p * 4096 + t * 8);
    // s_dst stage
    *(f32x4*)&dlds[t * 4] = *(const f32x4*)(s_dst + b * Nn + t * 4);

    const unsigned int key = md_key[b];
    const unsigned int mb_ = (key & 0x80000000u) ? (key ^ 0x80000000u) : ~key;
    const float mdb = __builtin_bit_cast(float, mb_);
    const int r0 = i0 + rg * 32 + n16;           // lane's first i-row
    const float ssr0 = s_src[b * Nn + r0];
    const float ssr1 = s_src[b * Nn + r0 + 16];
    const float tm0 = ssr0 + mdb, tm1 = ssr1 + mdb;
    const float mi0 = fmaxf(tm0, GAT_ALPHA * tm0) * LOG2E;
    const float mi1 = fmaxf(tm1, GAT_ALPHA * tm1) * LOG2E;
    const float sL0 = ssr0 * LOG2E, sL1 = ssr1 * LOG2E;
    const int jw = (jwin << 5) + (quad << 3);    // lane's j offset in 128-j tile
    const int mrow0 = (rg * 32 + n16) * MS;
    const int mrow1 = mrow0 + 16 * MS;

    // ballot tile 0 + mask write
    #pragma unroll
    for (int k = 0; k < 16; ++k) {
        unsigned long long m = __ballot(av[k] > 0);
        const int rr = k >> 1, c = k & 1;
        if (lane == 0) mlds[(w * 8 + rr) * MS + (c << 1)]     = (unsigned int)m;
        if (lane == 1) mlds[(w * 8 + rr) * MS + (c << 1) + 1] = (unsigned int)(m >> 32);
    }
    // Wp tile-0 ds_write (conflict-free linear, 4 passes of 16 B/thread)
    #pragma unroll
    for (int p = 0; p < 4; ++p)
        *(f32x4*)&ldsw[p * 4096 + t * 8] = pg[p];

    f32x4 acc[2][8] = {};
    float ls0 = 0.f, ls1 = 0.f;
    __syncthreads();

    // ---- main loop: 16 x 128-j tiles ----
    for (int s = 0; s < 16; ++s) {
        const int cur = s & 1, nxt = cur ^ 1;
        const int j0 = s << 7;
        // issue adj loads for tile s+1 (consumed by ballot at tile bottom)
        if (s < 15) {
            const int coff = (s + 1) << 7;
            #pragma unroll
            for (int k = 0; k < 16; ++k)
                av[k] = abase[(size_t)(k >> 1) * Nn + coff + ((k & 1) << 6)];
        }
        // issue Wp stage loads for tile s+1
        f32x4 g[4];
        if (s < 15) {
            const unsigned short* src = wsrc + (size_t)(s + 1) * 16384;
            #pragma unroll
            for (int p = 0; p < 4; ++p)
                g[p] = *(const f32x4*)(src + p * 4096 + t * 8);
        }
        // masks + d-values for this tile (LDS)
        const unsigned int mw0 = mlds[mrow0 + (s << 2) + jwin];
        const unsigned int mw1 = mlds[mrow1 + (s << 2) + jwin];
        const unsigned int mb0 = (mw0 >> (quad << 3)) & 0xffu;
        const unsigned int mb1 = (mw1 >> (quad << 3)) & 0xffu;
        f32x4 d0 = *(const f32x4*)&dlds[j0 + jw];
        f32x4 d1 = *(const f32x4*)&dlds[j0 + jw + 4];

        // exp -> two A fragments (rows r0 and r0+16)
        bf16x8 af0, af1;
        #pragma unroll
        for (int j = 0; j < 4; ++j) {
            {   float u  = __builtin_fmaf(d0[j], LOG2E, sL0);
                float lr = fmaxf(u, GAT_ALPHA * u);
                float e  = __builtin_amdgcn_exp2f(lr - mi0);
                e = ((mb0 >> j) & 1u) ? e : 0.f;
                unsigned short us = f2bf(e);
                ls0 += bf2f(us); af0[j] = (short)us; }
            {   float u  = __builtin_fmaf(d1[j], LOG2E, sL0);
                float lr = fmaxf(u, GAT_ALPHA * u);
                float e  = __builtin_amdgcn_exp2f(lr - mi0);
                e = ((mb0 >> (4 + j)) & 1u) ? e : 0.f;
                unsigned short us = f2bf(e);
                ls0 += bf2f(us); af0[4 + j] = (short)us; }
            {   float u  = __builtin_fmaf(d0[j], LOG2E, sL1);
                float lr = fmaxf(u, GAT_ALPHA * u);
                float e  = __builtin_amdgcn_exp2f(lr - mi1);
                e = ((mb1 >> j) & 1u) ? e : 0.f;
                unsigned short us = f2bf(e);
                ls1 += bf2f(us); af1[j] = (short)us; }
            {   float u  = __builtin_fmaf(d1[j], LOG2E, sL1);
                float lr = fmaxf(u, GAT_ALPHA * u);
                float e  = __builtin_amdgcn_exp2f(lr - mi1);
                e = ((mb1 >> (4 + j)) & 1u) ? e : 0.f;
                unsigned short us = f2bf(e);
                ls1 += bf2f(us); af1[4 + j] = (short)us; }
        }

        // B fragments from LDS (each feeds BOTH row-groups) + 16 MFMA
        const unsigned short* bbase = &ldsw[cur * 16384 + (jwin << 12) + (lane << 3)];
        #pragma unroll
        for (int nt = 0; nt < 8; ++nt) {
            bf16x8 bfr = *(const bf16x8*)(bbase + (nt << 9));
            acc[0][nt] = __builtin_amdgcn_mfma_f32_16x16x32_bf16(af0, bfr, acc[0][nt], 0, 0, 0);
            acc[1][nt] = __builtin_amdgcn_mfma_f32_16x16x32_bf16(af1, bfr, acc[1][nt], 0, 0, 0);
        }

        // ballot tile s+1 (adj loads had the whole tile to complete) + stage write
        if (s < 15) {
            #pragma unroll
            for (int k = 0; k < 16; ++k) {
                unsigned long long m = __ballot(av[k] > 0);
                const int rr = k >> 1, c = k & 1;
                const int wd = ((s + 1) << 2) + (c << 1);
                if (lane == 0) mlds[(w * 8 + rr) * MS + wd]     = (unsigned int)m;
                if (lane == 1) mlds[(w * 8 + rr) * MS + wd + 1] = (unsigned int)(m >> 32);
            }
            #pragma unroll
            for (int p = 0; p < 4; ++p)
                *(f32x4*)&ldsw[nxt * 16384 + p * 4096 + t * 8] = g[p];
        }
        __syncthreads();
    }

    // denominator: reduce per-lane partials across quads, atomics per wave
    ls0 += __shfl_xor(ls0, 16); ls0 += __shfl_xor(ls0, 32);
    ls1 += __shfl_xor(ls1, 16); ls1 += __shfl_xor(ls1, 32);
    if (quad == 0) {
        atomicAdd(&l_red[rg * 32 + n16], ls0);
        atomicAdd(&l_red[rg * 32 + 16 + n16], ls1);
    }

    // cross-wave acc reduction: jwin 0/1 write slots A/B; jwin 2/3 add
    float* slot = smem_f + (size_t)(jwin & 1) * (64 * AS);
    const int rbase = rg * 32;
    if (jwin < 2) {
        #pragma unroll
        for (int ig = 0; ig < 2; ++ig)
            #pragma unroll
            for (int nt = 0; nt < 8; ++nt)
                #pragma unroll
                for (int rr = 0; rr < 4; ++rr)
                    slot[(size_t)(rbase + ig * 16 + quad * 4 + rr) * AS + nt * 16 + n16] = acc[ig][nt][rr];
    }
    __syncthreads();
    if (jwin >= 2) {
        #pragma unroll
        for (int ig = 0; ig < 2; ++ig)
            #pragma unroll
            for (int nt = 0; nt < 8; ++nt)
                #pragma unroll
                for (int rr = 0; rr < 4; ++rr)
                    slot[(size_t)(rbase + ig * 16 + quad * 4 + rr) * AS + nt * 16 + n16] += acc[ig][nt][rr];
    }
    __syncthreads();

    // normalize + ELU + coalesced store (64 rows x 128 f)
    float* ob = out + ((size_t)(b * Nn + i0)) * FO;
    #pragma unroll
    for (int c = 0; c < 4; ++c) {
        int flat = c * 2048 + t * 4;
        int m = flat >> 7, f = flat & 127;
        f32x4 v0 = *(const f32x4*)&smem_f[(size_t)m * AS + f];
        f32x4 v1 = *(const f32x4*)&smem_f[(size_t)(64 + m) * AS + f];
        float l = l_red[m];
        f32x4 o;
        #pragma unroll
        for (int j = 0; j < 4; ++j) {
            float x = (v0[j] + v1[j]) / l;
            o[j] = x > 0.f ? x : expm1f(x);
        }
        *(f32x4*)&ob[(size_t)m * FO + f] = o;
    }
}

extern "C" void kernel_launch(void* const* d_in, const int* in_sizes, int n_in,
                              void* d_out, int out_size, void* d_ws, size_t ws_size,
                              hipStream_t stream)
{
    const float* h   = (const float*)d_in[0];
    const int*   adj = (const int*)d_in[1];
    const float* W   = (const float*)d_in[2];
    const float* a   = (const float*)d_in[3];
    float* out = (float*)d_out;

    char* ws = (char*)d_ws;
    unsigned short* Wp  = (unsigned short*)ws;                    // 4 MiB packed
    float* s_src        = (float*)(ws + 4194304);                 // 8 KiB
    float* s_dst        = (float*)(ws + 4259840);                 // 8 KiB
    float* wa           = (float*)(ws + 4325376);                 // 2 KiB
    unsigned int* md_key= (unsigned int*)(ws + 4327424);          // 32 B

    hipLaunchKernelGGL(gat_prep, dim3(8),   dim3(256), 0, stream, W, a, wa, md_key);
    hipLaunchKernelGGL(gat_wh,   dim3(256), dim3(256), 0, stream, h, W, wa, Wp, s_src, s_dst, md_key);
    hipLaunchKernelGGL(gat_attn, dim3(256), dim3(512), 0, stream, adj, Wp, s_src, s_dst, md_key, out);
}